// Round 13
// baseline (584.807 us; speedup 1.0000x reference)
//
#include <hip/hip_runtime.h>

typedef __bf16 bf16x8 __attribute__((ext_vector_type(8)));
typedef float f32x4 __attribute__((ext_vector_type(4)));
typedef int   i32x4 __attribute__((ext_vector_type(4)));

// LDS-only barrier: does NOT drain vmcnt, so global prefetch loads / fire-and-forget
// stores stay in flight across the barrier (CK block_sync_lds pattern).
__device__ __forceinline__ void sync_lds() {
    asm volatile("s_waitcnt lgkmcnt(0)" ::: "memory");
    __builtin_amdgcn_s_barrier();
}

// ---------------- fused prep: [0,7680) DFT basis | [7680,37920) frames | [37920,39200) WT ----------------
// WT row order is [dir][cell][gate] (n = dir*512 + jj*4 + g) so the mode-1 GEMM's pre
// scatter becomes lane-consecutive (dense 4B stores, no write amplification).
__global__ __launch_bounds__(256) void prep_kernel(
    const float* __restrict__ x, const float* __restrict__ w_ih_f, const float* __restrict__ w_ih_b,
    __bf16* __restrict__ BT, __bf16* __restrict__ A, __bf16* __restrict__ WT)
{
    int blk = blockIdx.x;
    if (blk < 7680) {                       // ---- DFT basis (v_cos/v_sin take REVOLUTIONS)
        int id = blk * 256 + threadIdx.x;   // < 2048*960
        int n = id / 960;
        int j = id - n * 960;
        int k = n >> 1;                                 // bin 0..1023
        int p = (k * (544 + j)) & 2047;                 // exact integer phase reduction
        float pr = (float)p * (1.0f / 2048.0f);         // revolutions
        float v = (n & 1) ? __builtin_amdgcn_sinf(pr) : __builtin_amdgcn_cosf(pr);
        BT[id] = (__bf16)v;
    } else if (blk < 37920) {               // ---- windowed frames: A[frame][j] = xp[t*240+544+j]*hann960[j]
        int id = (blk - 7680) * 256 + threadIdx.x;      // one thread per 2 cols, < 16128*480
        int frame = id / 480;
        int jp = (id - frame * 480) * 2;
        float v[2] = {0.f, 0.f};
        if (frame < 16016) {
            int b = frame / 1001;
            int t = frame - b * 1001;
            const float* xb = x + (size_t)b * 240000;
            #pragma unroll
            for (int e = 0; e < 2; ++e) {
                int j = jp + e;
                int s = t * 240 + j - 480;              // xp index minus pad
                if (s < 0) s = -s;                      // left reflect
                else if (s >= 240000) s = 479998 - s;   // right reflect (2L-2-s)
                float win = 0.5f - 0.5f * __builtin_amdgcn_cosf((float)j * (1.0f / 960.0f));
                v[e] = xb[s] * win;
            }
        }
        union { unsigned int u; __bf16 h[2]; } pk;
        pk.h[0] = (__bf16)v[0]; pk.h[1] = (__bf16)v[1];
        *reinterpret_cast<unsigned int*>(&A[(size_t)frame * 960 + jp]) = pk.u;
    } else {                                // ---- stacked input-proj weights, transposed + K-padded,
        int id = (blk - 37920) * 256 + threadIdx.x;     // gate-interleaved rows; < 1024*320
        int n = id / 320;
        int k = id - n * 320;
        int rem = n & 511;
        int srcrow = (rem & 3) * 128 + (rem >> 2);      // [g][jj] source row for [jj][g] dest row
        float v = 0.f;
        if (k < 301) v = (n < 512) ? w_ih_f[srcrow * 301 + k] : w_ih_b[srcrow * 301 + k];
        WT[id] = (__bf16)v;
    }
}

// ---------------- 256^2-tile DFT GEMM: Espec = energy of A(16128x960) * BT(2048x960)^T.
// 8 waves (2M x 4N), per-wave 128x64 output, double-buffered 128KB LDS. Per K-tile:
// issue ALL 8 global_load_lds for tile t+1 FIRST (HBM latency hides under ~550 cyc of
// MFMA), then 24 ds_read_b128 + 64 MFMA for tile t, then ONE __syncthreads (own-wave
// vmcnt(0) is nearly free -- loads were issued a full tile earlier). Same chunk-XOR
// swizzle + fragment mapping as the proven 128^2 kernel. Epilogue: e = c0^2+c1^2 via
// shfl_xor, one bf16 energy per bin. ----------------
__global__ __launch_bounds__(512) void gemm_dft(
    const __bf16* __restrict__ A, const __bf16* __restrict__ BT,
    __bf16* __restrict__ Espec)
{
    __shared__ __bf16 Abuf[2][256 * 64];
    __shared__ __bf16 Bbuf[2][256 * 64];
    const int tid = threadIdx.x;
    const int wave = tid >> 6, lane = tid & 63, l15 = lane & 15, quad = lane >> 4;
    const int wm = wave >> 2, wn = wave & 3;          // 2 x 4 wave grid
    const int bid = blockIdx.x;                       // 504 = 63 bm x 8 bn
    const int bm = bid >> 3, bn = bid & 7;
    const int rl  = lane >> 3;
    const int gch = (lane & 7) ^ rl;                  // swizzled global 16B-chunk
    const int Ka = 960;
    const __bf16* Ag = A  + (size_t)(bm * 256) * Ka;
    const __bf16* Bg = BT + (size_t)(bn * 256) * Ka;

    f32x4 acc[8][4] = {};

    auto stage = [&](int buf, int k0) {
        #pragma unroll
        for (int p = 0; p < 4; ++p) {
            int c = wave + p * 8;          // 32 chunks (8 rows each) over 8 waves
            int row = c * 8 + rl;
            __builtin_amdgcn_global_load_lds(
                (const __attribute__((address_space(1))) void*)(Ag + (size_t)row * Ka + k0 + gch * 8),
                (__attribute__((address_space(3))) void*)(&Abuf[buf][c * 512]), 16, 0, 0);
            __builtin_amdgcn_global_load_lds(
                (const __attribute__((address_space(1))) void*)(Bg + (size_t)row * Ka + k0 + gch * 8),
                (__attribute__((address_space(3))) void*)(&Bbuf[buf][c * 512]), 16, 0, 0);
        }
    };

    stage(0, 0);
    __syncthreads();

    for (int t = 0; t < 15; ++t) {
        int cur = t & 1;
        if (t < 14) stage(cur ^ 1, (t + 1) * 64);     // issue-early: next tile's loads
        const __bf16* As = Abuf[cur];
        const __bf16* Bs = Bbuf[cur];
        #pragma unroll
        for (int kk = 0; kk < 2; ++kk) {
            bf16x8 bfr[4];
            #pragma unroll
            for (int j = 0; j < 4; ++j) {
                int r = wn * 64 + j * 16 + l15;
                int ch = (kk * 4 + quad) ^ (l15 & 7);
                bfr[j] = *reinterpret_cast<const bf16x8*>(&Bs[r * 64 + ch * 8]);
            }
            #pragma unroll
            for (int i = 0; i < 8; ++i) {
                int r = wm * 128 + i * 16 + l15;
                int ch = (kk * 4 + quad) ^ (l15 & 7);
                bf16x8 af = *reinterpret_cast<const bf16x8*>(&As[r * 64 + ch * 8]);
                #pragma unroll
                for (int j = 0; j < 4; ++j)
                    acc[i][j] = __builtin_amdgcn_mfma_f32_16x16x32_bf16(af, bfr[j], acc[i][j], 0, 0, 0);
            }
        }
        __syncthreads();   // own vmcnt(0)+lgkmcnt(0)+barrier: next tile's LDS complete for ALL waves
    }

    #pragma unroll
    for (int i = 0; i < 8; ++i)
        #pragma unroll
        for (int j = 0; j < 4; ++j) {
            int n = bn * 256 + wn * 64 + j * 16 + l15;
            #pragma unroll
            for (int r = 0; r < 4; ++r) {
                float v = acc[i][j][r];
                float u = __shfl_xor(v, 1, 64);   // partner lane holds the sin/cos twin
                float e = v * v + u * u;
                if ((l15 & 1) == 0) {             // even lane owns the bin
                    int m = bm * 256 + wm * 128 + i * 16 + quad * 4 + r;
                    Espec[(size_t)m * 1024 + (n >> 1)] = (__bf16)e;
                }
            }
        }
}

// ---------------- bf16 MFMA GEMM (mode 1 only now): input projection, 128x64 tiles,
// dense fp32 store into [t][dir][batch][cell][gate] `pre` + bias, PRE-SCALED by the
// gate's exp2 multiplier gamma_g; gate-interleaved weight rows -> lane-consecutive. ----------------
__global__ __launch_bounds__(256) void gemm_kernel(
    const __bf16* __restrict__ A, const __bf16* __restrict__ BT,
    int Ka, int kIters, int mode,
    __bf16* __restrict__ Espec, float* __restrict__ pre,
    const float* __restrict__ b_f, const float* __restrict__ b_b)
{
    __shared__ __bf16 As[128 * 64];
    __shared__ __bf16 Bs[128 * 64];
    const int tid = threadIdx.x;
    const int wave = tid >> 6, lane = tid & 63, l15 = lane & 15, quad = lane >> 4;
    const int bn = blockIdx.x, bm = blockIdx.y;
    const int qm = wave >> 1, qn = wave & 1;
    f32x4 acc[4][4] = {};
    const int rl  = lane >> 3;            // row within 8-row chunk
    const int gch = (lane & 7) ^ rl;      // swizzled global 16B-chunk within the 64-col row
    const __bf16* Ag = A + (size_t)(bm * 128) * Ka;
    const __bf16* Bg = BT + (size_t)(bn * 128) * Ka;

    for (int kb = 0; kb < kIters; ++kb) {
        int k0 = kb * 64;
        #pragma unroll
        for (int p = 0; p < 4; ++p) {
            int c = wave + p * 4;          // 16 chunk-instructions cover 128 rows (8 rows each)
            int row = c * 8 + rl;
            __builtin_amdgcn_global_load_lds(
                (const __attribute__((address_space(1))) void*)(Ag + (size_t)row * Ka + k0 + gch * 8),
                (__attribute__((address_space(3))) void*)(As + c * 512), 16, 0, 0);
            __builtin_amdgcn_global_load_lds(
                (const __attribute__((address_space(1))) void*)(Bg + (size_t)row * Ka + k0 + gch * 8),
                (__attribute__((address_space(3))) void*)(Bs + c * 512), 16, 0, 0);
        }
        __syncthreads();
        #pragma unroll
        for (int ks = 0; ks < 2; ++ks) {
            bf16x8 af[4], bfr[4];
            #pragma unroll
            for (int i = 0; i < 4; ++i) {
                int row = qm * 64 + i * 16 + l15;
                int ch = (ks * 4 + quad) ^ (l15 & 7);
                af[i] = *reinterpret_cast<const bf16x8*>(&As[row * 64 + ch * 8]);
            }
            #pragma unroll
            for (int j = 0; j < 4; ++j) {
                int row = qn * 64 + j * 16 + l15;
                int ch = (ks * 4 + quad) ^ (l15 & 7);
                bfr[j] = *reinterpret_cast<const bf16x8*>(&Bs[row * 64 + ch * 8]);
            }
            #pragma unroll
            for (int i = 0; i < 4; ++i)
                #pragma unroll
                for (int j = 0; j < 4; ++j)
                    acc[i][j] = __builtin_amdgcn_mfma_f32_16x16x32_bf16(af[i], bfr[j], acc[i][j], 0, 0, 0);
        }
        __syncthreads();
    }

    if (mode == 0) {
        #pragma unroll
        for (int i = 0; i < 4; ++i)
            #pragma unroll
            for (int j = 0; j < 4; ++j) {
                int n = bn * 128 + qn * 64 + j * 16 + l15;
                #pragma unroll
                for (int r = 0; r < 4; ++r) {
                    float v = acc[i][j][r];
                    float u = __shfl_xor(v, 1, 64);
                    float e = v * v + u * u;
                    if ((l15 & 1) == 0) {
                        int m = bm * 128 + qm * 64 + i * 16 + quad * 4 + r;
                        Espec[(size_t)m * 1024 + (n >> 1)] = (__bf16)e;
                    }
                }
            }
    } else {
        const float L2E = 1.4426950408889634f;
        for (int i = 0; i < 4; ++i)
            for (int j = 0; j < 4; ++j) {
                int n = bn * 128 + qn * 64 + j * 16 + l15;   // n < 1024, gate-interleaved rows
                int dirg = n >> 9;
                int rem = n & 511;                           // jj*4 + g
                int g = n & 3;
                int srcrow = g * 128 + (rem >> 2);           // bias lives in [g][jj] order
                float bias = (dirg == 0) ? b_f[srcrow] : b_b[srcrow];
                float gam = (g == 2) ? (-2.f * L2E) : (-L2E);
                for (int r = 0; r < 4; ++r) {
                    int m = bm * 128 + qm * 64 + i * 16 + quad * 4 + r;
                    if (m < 16016) {
                        int b = m / 1001;
                        int t = m - b * 1001;
                        // pre[t][dirg][batch b][rem]  (pre-scaled by gamma_g), dense in rem
                        size_t off = ((size_t)(t * 2 + dirg) * 16 + b) * 512 + rem;
                        pre[off] = gam * (acc[i][j][r] + bias);
                    }
                }
            }
    }
}

// ---------------- feature build: stage the frame's 2KB ENERGY row into LDS with
// coalesced global_load_lds (waves 0-1), then gather harmonics from LDS. ----------------
__global__ __launch_bounds__(256) void build_feat(const float* __restrict__ f0,
    const __bf16* __restrict__ Espec, __bf16* __restrict__ feat)
{
    __shared__ __bf16 row[1024];
    const int frame = blockIdx.x;
    const int tid = threadIdx.x;
    // 128 threads x 16B = 2048B = whole energy row, coalesced
    if (tid < 128)
        __builtin_amdgcn_global_load_lds(
            (const __attribute__((address_space(1))) void*)(Espec + (size_t)frame * 1024 + tid * 8),
            (__attribute__((address_space(3))) void*)(row + (tid >> 6) * 512), 16, 0, 0);

    int b = frame / 1001;
    int t = frame - b * 1001;
    float f0v = f0[b * 1001 + t];
    float f0nz = (f0v > 0.f) ? f0v : 80.f;   // SR/NUM_BANDS*0.5
    __syncthreads();                         // drains vmcnt -> row[] valid

    const float LN2 = 0.6931471805599453f;
    for (int d = tid; d < 320; d += 256) {
        float val = 0.f;
        if (d < 300) {
            float mult = (d == 0) ? 0.5f : (float)(d + 1) * 0.5f;
            int kidx = (int)rintf(f0nz * mult * (1.0f / 11.71875f));  // FREQ_INTERVAL = 24000/2048
            kidx = min(max(kidx, 0), 1024);
            float e = 0.f;
            if (kidx < 1024) e = (float)row[kidx];   // bin 1024 forced to zero by reference
            val = (__builtin_amdgcn_logf(e + 1e-8f) * LN2 + 18.f) * (1.f / 23.f);
        } else if (d == 300) {
            val = __builtin_amdgcn_logf(f0nz) * LN2;
        }
        feat[(size_t)frame * 320 + d] = (__bf16)val;
    }
}

// ---------------- batch-parallel BiLSTM: 32 blocks = (batch 16) x (dir 2), one CU each.
// Measured floor (R6/R8/R11/R12: ~358 us). 4 waves, i8 MFMA 16x16x64 recurrent matvec,
// 8-deep acc select, fused gate chain with gamma folded into pre. Step ~859 cyc =
// 320 (per-SIMD MFMA pipe) + ~535 (serial recurrence) — additive, confirmed by R10. ----------------
__global__ __launch_bounds__(256) void lstm_kernel(
    const float* __restrict__ w_hh_f, const float* __restrict__ w_hh_b,
    const float* __restrict__ pre, float* __restrict__ h_out)
{
    const int bid = blockIdx.x;          // 0..31
    const int b   = bid & 15;
    const int dir = bid >> 4;
    const float* w_hh = dir ? w_hh_b : w_hh_f;
    const int tid = threadIdx.x;
    const int wave = tid >> 6, lane = tid & 63, l15 = lane & 15, quad = lane >> 4;
    const bool own = ((l15 & 1) == 0);               // lane pairs share a cell; even l15 writes
    const int cellj = wave * 32 + ((l15 >> 1) << 2) + quad;
    const int m0 = (l15 >> 1) & 1, m1 = (l15 >> 2) & 1, m2 = (l15 >> 3) & 1;  // select bits

    __shared__ __attribute__((aligned(16))) signed char h8[2][128];   // double-buffered i8 h(t)

    // A-fragments (i8): perm row s = wave*128 + mt*16 + l15; W_hh row = (s&3)*128 + (s>>2)
    // frag element: byte e (=d*4+bi) of kt covers k = kt*64 + quad*16 + e
    i32x4 afrag[8][2];
    #pragma unroll
    for (int mt = 0; mt < 8; ++mt) {
        int s = wave * 128 + mt * 16 + l15;
        const float* wrow = w_hh + (size_t)((s & 3) * 128 + (s >> 2)) * 128;
        #pragma unroll
        for (int kt = 0; kt < 2; ++kt) {
            i32x4 v;
            #pragma unroll
            for (int d = 0; d < 4; ++d) {
                int pk = 0;
                #pragma unroll
                for (int bi = 0; bi < 4; ++bi) {
                    int k = kt * 64 + quad * 16 + d * 4 + bi;
                    int q = (int)rintf(wrow[k] * 254.f);
                    pk |= (q & 255) << (bi * 8);
                }
                v[d] = pk;
            }
            afrag[mt][kt] = v;
        }
    }

    if (tid < 64) reinterpret_cast<int*>(h8)[tid] = 0;   // zero both 128B buffers

    const int t0 = dir ? 1000 : 0;
    const ptrdiff_t pre_sstride  = dir ? -16384 : 16384;   // floats per step
    const ptrdiff_t hout_sstride = dir ? -2048  : 2048;    // floats per step
    const float* pre_base = pre + ((size_t)(t0 * 2 + dir) * 16 + b) * 512 + (size_t)cellj * 4;
    float* hout_base = h_out + (((size_t)dir * 1001 + t0) * 16 + b) * 128 + cellj;

    float cstate = 0.f;
    const float L2E = 1.4426950408889634f;
    const float DF = 1.0f / (254.f * 127.f);
    const float CI = -L2E * DF;          // i, f, o gates
    const float CG = -2.f * L2E * DF;    // g gate

    auto body = [&](int s, f32x4 P) {
        const signed char* hb = h8[s & 1];
        i32x4 b0 = *reinterpret_cast<const i32x4*>(&hb[quad * 16]);
        i32x4 b1 = *reinterpret_cast<const i32x4*>(&hb[64 + quad * 16]);

        i32x4 acc[8] = {};
        #pragma unroll
        for (int mt = 0; mt < 8; ++mt)
            acc[mt] = __builtin_amdgcn_mfma_i32_16x16x64_i8(afrag[mt][0], b0, acc[mt], 0, 0, 0);
        #pragma unroll
        for (int mt = 0; mt < 8; ++mt)
            acc[mt] = __builtin_amdgcn_mfma_i32_16x16x64_i8(afrag[mt][1], b1, acc[mt], 0, 0, 0);

        // z4 = acc[l15>>1] (3-level select; valid for this lane's cell)
        i32x4 ta = m0 ? acc[1] : acc[0];
        i32x4 tb = m0 ? acc[3] : acc[2];
        i32x4 tc = m0 ? acc[5] : acc[4];
        i32x4 td = m0 ? acc[7] : acc[6];
        i32x4 ua = m1 ? tb : ta;
        i32x4 ub = m1 ? td : tc;
        i32x4 z4 = m2 ? ub : ua;

        // gates: pre already carries gamma_g*(z_in+bias); one cvt+fma per gate
        float ai = fmaf((float)z4[0], CI, P[0]);
        float af_ = fmaf((float)z4[1], CI, P[1]);
        float ag = fmaf((float)z4[2], CG, P[2]);
        float ao = fmaf((float)z4[3], CI, P[3]);
        float A = __builtin_amdgcn_exp2f(ai);
        float B = __builtin_amdgcn_exp2f(af_);
        float C = __builtin_amdgcn_exp2f(ag);
        float D = __builtin_amdgcn_exp2f(ao);
        float Pp = (1.f + A) * (1.f + C);
        float Q = 1.f + B;
        float cn = (cstate * Pp + (1.f - C) * Q) * __builtin_amdgcn_rcpf(Pp * Q);
        cstate = cn;
        float E = __builtin_amdgcn_exp2f(-2.f * L2E * cn);
        float h = (1.f - E) * __builtin_amdgcn_rcpf((1.f + D) * (1.f + E));

        if (own) {
            h8[(s + 1) & 1][cellj] = (signed char)(int)rintf(h * 127.f);
            hout_base[(ptrdiff_t)s * hout_sstride] = h;   // fire-and-forget
        }
    };

    auto load_pre = [&](int sidx) -> f32x4 {
        return *reinterpret_cast<const f32x4*>(pre_base + (ptrdiff_t)sidx * pre_sstride);
    };

    f32x4 P0 = load_pre(0), P1 = load_pre(1), P2 = load_pre(2), P3 = load_pre(3);
    __syncthreads();   // h8 init visible

    for (int s = 0; s < 1000; s += 4) {   // pre padded +-4 steps: no bounds checks
        body(s, P0);     P0 = load_pre(s + 4); sync_lds();
        body(s + 1, P1); P1 = load_pre(s + 5); sync_lds();
        body(s + 2, P2); P2 = load_pre(s + 6); sync_lds();
        body(s + 3, P3); P3 = load_pre(s + 7); sync_lds();
    }
    body(1000, P0);
}

// ---------------- LayerNorm + out projection via MFMA: 1001 blocks x 16 rows. ----------------
__global__ __launch_bounds__(256) void out_kernel(
    const float* __restrict__ h_out, const float* __restrict__ ln_g, const float* __restrict__ ln_b,
    const float* __restrict__ out_w, const float* __restrict__ out_b, float* __restrict__ out)
{
    __shared__ __bf16 hn_lds[16 * 264];   // stride 264 -> 2-way on b128 = free
    const int tid = threadIdx.x;
    const int wave = tid >> 6, lane = tid & 63, l15 = lane & 15, quad = lane >> 4;

    float lg0 = ln_g[lane],        lb0 = ln_b[lane];
    float lg1 = ln_g[64 + lane],   lb1 = ln_b[64 + lane];
    float lg2 = ln_g[128 + lane],  lb2 = ln_b[128 + lane];
    float lg3 = ln_g[192 + lane],  lb3 = ln_b[192 + lane];

    #pragma unroll
    for (int rr = 0; rr < 4; ++rr) {
        int wrow = wave * 4 + rr;
        int r = blockIdx.x * 16 + wrow;            // 1001*16 = 16016 exactly: no guard
        int b = r / 1001, t = r - b * 1001;
        size_t basef = ((size_t)t * 16 + b) * 128;            // dir 0
        size_t baseb = ((size_t)(1001 + t) * 16 + b) * 128;   // dir 1
        float h0 = h_out[basef + lane];
        float h1 = h_out[basef + 64 + lane];
        float h2 = h_out[baseb + lane];
        float h3 = h_out[baseb + 64 + lane];
        float s1 = h0 + h1 + h2 + h3;
        float s2 = h0 * h0 + h1 * h1 + h2 * h2 + h3 * h3;
        #pragma unroll
        for (int m = 32; m >= 1; m >>= 1) {
            s1 += __shfl_xor(s1, m, 64);
            s2 += __shfl_xor(s2, m, 64);
        }
        float mu = s1 * (1.f / 256.f);
        float var = s2 * (1.f / 256.f) - mu * mu;   // biased var, matches jnp var
        float rstd = rsqrtf(var + 1e-5f);
        hn_lds[wrow * 264 + lane]       = (__bf16)((h0 - mu) * rstd * lg0 + lb0);
        hn_lds[wrow * 264 + 64 + lane]  = (__bf16)((h1 - mu) * rstd * lg1 + lb1);
        hn_lds[wrow * 264 + 128 + lane] = (__bf16)((h2 - mu) * rstd * lg2 + lb2);
        hn_lds[wrow * 264 + 192 + lane] = (__bf16)((h3 - mu) * rstd * lg3 + lb3);
    }
    __syncthreads();

    // GEMM: out[16 rows][64 cols] = hn(16x256) . out_w(64x256)^T; wave covers 16 cols
    const int o = wave * 16 + l15;
    f32x4 accA = {}, accB = {};
    #pragma unroll
    for (int kt = 0; kt < 8; ++kt) {
        bf16x8 a = *reinterpret_cast<const bf16x8*>(&hn_lds[l15 * 264 + kt * 32 + quad * 8]);
        const float* wp = out_w + (size_t)o * 256 + kt * 32 + quad * 8;
        bf16x8 bv;
        #pragma unroll
        for (int e = 0; e < 8; ++e) bv[e] = (__bf16)wp[e];
        if (kt & 1) accB = __builtin_amdgcn_mfma_f32_16x16x32_bf16(a, bv, accB, 0, 0, 0);
        else        accA = __builtin_amdgcn_mfma_f32_16x16x32_bf16(a, bv, accA, 0, 0, 0);
    }
    f32x4 acc = accA + accB;
    float ob = out_b[o];
    #pragma unroll
    for (int rc = 0; rc < 4; ++rc) {
        int r = blockIdx.x * 16 + quad * 4 + rc;
        out[(size_t)r * 64 + o] = acc[rc] + ob;
    }
}

extern "C" void kernel_launch(void* const* d_in, const int* in_sizes, int n_in,
                              void* d_out, int out_size, void* d_ws, size_t ws_size,
                              hipStream_t stream) {
    const float* x      = (const float*)d_in[0];
    const float* f0     = (const float*)d_in[1];
    const float* w_ih_f = (const float*)d_in[2];
    const float* w_hh_f = (const float*)d_in[3];
    const float* b_f    = (const float*)d_in[4];
    const float* w_ih_b = (const float*)d_in[5];
    const float* w_hh_b = (const float*)d_in[6];
    const float* b_b    = (const float*)d_in[7];
    const float* ln_g   = (const float*)d_in[8];
    const float* ln_b   = (const float*)d_in[9];
    const float* out_w  = (const float*)d_in[10];
    const float* out_b  = (const float*)d_in[11];
    float* out = (float*)d_out;

    char* ws = (char*)d_ws;
    size_t off = 0;
    auto alloc = [&](size_t bytes) { size_t o = off; off = (off + bytes + 255) & ~(size_t)255; return o; };
    __bf16* A     = (__bf16*)(ws + alloc((size_t)16128 * 960 * 2));
    __bf16* BT    = (__bf16*)(ws + alloc((size_t)2048 * 960 * 2));
    __bf16* Espec = (__bf16*)(ws + alloc((size_t)16128 * 1024 * 2));
    __bf16* feat  = (__bf16*)(ws + alloc((size_t)16128 * 320 * 2));
    __bf16* WT    = (__bf16*)(ws + alloc((size_t)1024 * 320 * 2));
    // pre padded +-4 timesteps (8 dir-slots each side) so the depth-4 prefetch stays in-buffer
    float*  preA  = (float*)(ws + alloc((size_t)(1001 * 2 + 16) * 16 * 512 * 4));
    float*  pre   = preA + (size_t)8 * 16 * 512;
    float*  h_out = (float*)(ws + alloc((size_t)2 * 1001 * 16 * 128 * 4));
    (void)ws_size; (void)in_sizes; (void)n_in; (void)out_size;

    prep_kernel <<<39200, 256, 0, stream>>>(x, w_ih_f, w_ih_b, BT, A, WT);
    gemm_dft    <<<504, 512, 0, stream>>>(A, BT, Espec);
    build_feat  <<<16016, 256, 0, stream>>>(f0, Espec, feat);
    gemm_kernel <<<dim3(8, 126), 256, 0, stream>>>(feat, WT, 320, 5, 1, nullptr, pre, b_f, b_b);
    lstm_kernel <<<32, 256, 0, stream>>>(w_hh_f, w_hh_b, pre, h_out);
    out_kernel  <<<1001, 256, 0, stream>>>(h_out, ln_g, ln_b, out_w, out_b, out);
}

// Round 14
// 572.668 us; speedup vs baseline: 1.0212x; 1.0212x over previous
//
#include <hip/hip_runtime.h>

typedef __bf16 bf16x8 __attribute__((ext_vector_type(8)));
typedef float f32x4 __attribute__((ext_vector_type(4)));
typedef int   i32x4 __attribute__((ext_vector_type(4)));

// LDS-only barrier: does NOT drain vmcnt, so global prefetch loads / fire-and-forget
// stores stay in flight across the barrier (CK block_sync_lds pattern).
__device__ __forceinline__ void sync_lds() {
    asm volatile("s_waitcnt lgkmcnt(0)" ::: "memory");
    __builtin_amdgcn_s_barrier();
}

// ---------------- fused prep: [0,7680) DFT basis | [7680,37920) frames | [37920,39200) WT ----------------
// WT row order is [dir][cell][gate] (n = dir*512 + jj*4 + g) so the mode-1 GEMM's pre
// scatter becomes lane-consecutive (dense 4B stores, no write amplification).
__global__ __launch_bounds__(256) void prep_kernel(
    const float* __restrict__ x, const float* __restrict__ w_ih_f, const float* __restrict__ w_ih_b,
    __bf16* __restrict__ BT, __bf16* __restrict__ A, __bf16* __restrict__ WT)
{
    int blk = blockIdx.x;
    if (blk < 7680) {                       // ---- DFT basis (v_cos/v_sin take REVOLUTIONS)
        int id = blk * 256 + threadIdx.x;   // < 2048*960
        int n = id / 960;
        int j = id - n * 960;
        int k = n >> 1;                                 // bin 0..1023
        int p = (k * (544 + j)) & 2047;                 // exact integer phase reduction
        float pr = (float)p * (1.0f / 2048.0f);         // revolutions
        float v = (n & 1) ? __builtin_amdgcn_sinf(pr) : __builtin_amdgcn_cosf(pr);
        BT[id] = (__bf16)v;
    } else if (blk < 37920) {               // ---- windowed frames: A[frame][j] = xp[t*240+544+j]*hann960[j]
        int id = (blk - 7680) * 256 + threadIdx.x;      // one thread per 2 cols, < 16128*480
        int frame = id / 480;
        int jp = (id - frame * 480) * 2;
        float v[2] = {0.f, 0.f};
        if (frame < 16016) {
            int b = frame / 1001;
            int t = frame - b * 1001;
            const float* xb = x + (size_t)b * 240000;
            #pragma unroll
            for (int e = 0; e < 2; ++e) {
                int j = jp + e;
                int s = t * 240 + j - 480;              // xp index minus pad
                if (s < 0) s = -s;                      // left reflect
                else if (s >= 240000) s = 479998 - s;   // right reflect (2L-2-s)
                float win = 0.5f - 0.5f * __builtin_amdgcn_cosf((float)j * (1.0f / 960.0f));
                v[e] = xb[s] * win;
            }
        }
        union { unsigned int u; __bf16 h[2]; } pk;
        pk.h[0] = (__bf16)v[0]; pk.h[1] = (__bf16)v[1];
        *reinterpret_cast<unsigned int*>(&A[(size_t)frame * 960 + jp]) = pk.u;
    } else {                                // ---- stacked input-proj weights, transposed + K-padded,
        int id = (blk - 37920) * 256 + threadIdx.x;     // gate-interleaved rows; < 1024*320
        int n = id / 320;
        int k = id - n * 320;
        int rem = n & 511;
        int srcrow = (rem & 3) * 128 + (rem >> 2);      // [g][jj] source row for [jj][g] dest row
        float v = 0.f;
        if (k < 301) v = (n < 512) ? w_ih_f[srcrow * 301 + k] : w_ih_b[srcrow * 301 + k];
        WT[id] = (__bf16)v;
    }
}

// ---------------- bf16 MFMA GEMM, C = A(M x Ka) * BT(N x Ka)^T.  m97-style staging:
// global_load_lds width=16 into unpadded 128x64 tiles; XOR swizzle chunk^=(row&7) applied
// on the GLOBAL side -> fragment ds_read_b128 conflict-light.
// mode 0: DFT. cos/sin of one bin land in ADJACENT LANES (n differs in l15 bit0), so the
//   epilogue forms e = c0^2 + c1^2 via one shfl_xor and stores a single bf16 ENERGY per
//   bin (Espec, row stride 1024): halves the write AND build_feat's read vs storing
//   components, and the energy is rounded once from f32 (slightly more accurate).
//   1-D grid with XCD-aware remap (bid%8 == bm%8) keeps A-panel sharers on one L2.
// mode 1: input projection (dense fp32 store into [t][dir][batch][cell][gate] `pre`
//   + bias, PRE-SCALED by gamma_g; gate-interleaved weight rows -> lane-consecutive). ----------------
__global__ __launch_bounds__(256) void gemm_kernel(
    const __bf16* __restrict__ A, const __bf16* __restrict__ BT,
    int Ka, int kIters, int mode,
    __bf16* __restrict__ Espec, float* __restrict__ pre,
    const float* __restrict__ b_f, const float* __restrict__ b_b)
{
    __shared__ __bf16 As[128 * 64];
    __shared__ __bf16 Bs[128 * 64];
    const int tid = threadIdx.x;
    const int wave = tid >> 6, lane = tid & 63, l15 = lane & 15, quad = lane >> 4;
    int bn, bm;
    if (mode == 0) {                       // XCD-aware decode: bid%8 == bm%8
        int bid = blockIdx.x;              // grid 2048, 32 invalid ids exit (before any barrier)
        int xcd = bid & 7;
        int r = bid >> 3;
        bn = r & 15;
        bm = (r >> 4) * 8 + xcd;
        if (bm >= 126) return;
    } else {
        bn = blockIdx.x; bm = blockIdx.y;
    }
    const int qm = wave >> 1, qn = wave & 1;
    f32x4 acc[4][4] = {};
    const int rl  = lane >> 3;            // row within 8-row chunk
    const int gch = (lane & 7) ^ rl;      // swizzled global 16B-chunk within the 64-col row
    const __bf16* Ag = A + (size_t)(bm * 128) * Ka;
    const __bf16* Bg = BT + (size_t)(bn * 128) * Ka;

    for (int kb = 0; kb < kIters; ++kb) {
        int k0 = kb * 64;
        #pragma unroll
        for (int p = 0; p < 4; ++p) {
            int c = wave + p * 4;          // 16 chunk-instructions cover 128 rows (8 rows each)
            int row = c * 8 + rl;
            __builtin_amdgcn_global_load_lds(
                (const __attribute__((address_space(1))) void*)(Ag + (size_t)row * Ka + k0 + gch * 8),
                (__attribute__((address_space(3))) void*)(As + c * 512), 16, 0, 0);
            __builtin_amdgcn_global_load_lds(
                (const __attribute__((address_space(1))) void*)(Bg + (size_t)row * Ka + k0 + gch * 8),
                (__attribute__((address_space(3))) void*)(Bs + c * 512), 16, 0, 0);
        }
        __syncthreads();
        #pragma unroll
        for (int ks = 0; ks < 2; ++ks) {
            bf16x8 af[4], bfr[4];
            #pragma unroll
            for (int i = 0; i < 4; ++i) {
                int row = qm * 64 + i * 16 + l15;
                int ch = (ks * 4 + quad) ^ (l15 & 7);
                af[i] = *reinterpret_cast<const bf16x8*>(&As[row * 64 + ch * 8]);
            }
            #pragma unroll
            for (int j = 0; j < 4; ++j) {
                int row = qn * 64 + j * 16 + l15;
                int ch = (ks * 4 + quad) ^ (l15 & 7);
                bfr[j] = *reinterpret_cast<const bf16x8*>(&Bs[row * 64 + ch * 8]);
            }
            #pragma unroll
            for (int i = 0; i < 4; ++i)
                #pragma unroll
                for (int j = 0; j < 4; ++j)
                    acc[i][j] = __builtin_amdgcn_mfma_f32_16x16x32_bf16(af[i], bfr[j], acc[i][j], 0, 0, 0);
        }
        __syncthreads();
    }

    if (mode == 0) {
        #pragma unroll
        for (int i = 0; i < 4; ++i)
            #pragma unroll
            for (int j = 0; j < 4; ++j) {
                int n = bn * 128 + qn * 64 + j * 16 + l15;
                #pragma unroll
                for (int r = 0; r < 4; ++r) {
                    float v = acc[i][j][r];
                    float u = __shfl_xor(v, 1, 64);   // partner lane holds the sin/cos twin
                    float e = v * v + u * u;
                    if ((l15 & 1) == 0) {             // even lane owns the bin
                        int m = bm * 128 + qm * 64 + i * 16 + quad * 4 + r;
                        Espec[(size_t)m * 1024 + (n >> 1)] = (__bf16)e;
                    }
                }
            }
    } else {
        const float L2E = 1.4426950408889634f;
        for (int i = 0; i < 4; ++i)
            for (int j = 0; j < 4; ++j) {
                int n = bn * 128 + qn * 64 + j * 16 + l15;   // n < 1024, gate-interleaved rows
                int dirg = n >> 9;
                int rem = n & 511;                           // jj*4 + g
                int g = n & 3;
                int srcrow = g * 128 + (rem >> 2);           // bias lives in [g][jj] order
                float bias = (dirg == 0) ? b_f[srcrow] : b_b[srcrow];
                float gam = (g == 2) ? (-2.f * L2E) : (-L2E);
                for (int r = 0; r < 4; ++r) {
                    int m = bm * 128 + qm * 64 + i * 16 + quad * 4 + r;
                    if (m < 16016) {
                        int b = m / 1001;
                        int t = m - b * 1001;
                        // pre[t][dirg][batch b][rem]  (pre-scaled by gamma_g), dense in rem
                        size_t off = ((size_t)(t * 2 + dirg) * 16 + b) * 512 + rem;
                        pre[off] = gam * (acc[i][j][r] + bias);
                    }
                }
            }
    }
}

// ---------------- feature build: stage the frame's 2KB ENERGY row into LDS with
// coalesced global_load_lds (waves 0-1), then gather harmonics from LDS. ----------------
__global__ __launch_bounds__(256) void build_feat(const float* __restrict__ f0,
    const __bf16* __restrict__ Espec, __bf16* __restrict__ feat)
{
    __shared__ __bf16 row[1024];
    const int frame = blockIdx.x;
    const int tid = threadIdx.x;
    // 128 threads x 16B = 2048B = whole energy row, coalesced
    if (tid < 128)
        __builtin_amdgcn_global_load_lds(
            (const __attribute__((address_space(1))) void*)(Espec + (size_t)frame * 1024 + tid * 8),
            (__attribute__((address_space(3))) void*)(row + (tid >> 6) * 512), 16, 0, 0);

    int b = frame / 1001;
    int t = frame - b * 1001;
    float f0v = f0[b * 1001 + t];
    float f0nz = (f0v > 0.f) ? f0v : 80.f;   // SR/NUM_BANDS*0.5
    __syncthreads();                         // drains vmcnt -> row[] valid

    const float LN2 = 0.6931471805599453f;
    for (int d = tid; d < 320; d += 256) {
        float val = 0.f;
        if (d < 300) {
            float mult = (d == 0) ? 0.5f : (float)(d + 1) * 0.5f;
            int kidx = (int)rintf(f0nz * mult * (1.0f / 11.71875f));  // FREQ_INTERVAL = 24000/2048
            kidx = min(max(kidx, 0), 1024);
            float e = 0.f;
            if (kidx < 1024) e = (float)row[kidx];   // bin 1024 forced to zero by reference
            val = (__builtin_amdgcn_logf(e + 1e-8f) * LN2 + 18.f) * (1.f / 23.f);
        } else if (d == 300) {
            val = __builtin_amdgcn_logf(f0nz) * LN2;
        }
        feat[(size_t)frame * 320 + d] = (__bf16)val;
    }
}

// ---------------- batch-parallel BiLSTM: 32 blocks = (batch 16) x (dir 2), one CU each.
// Measured floor (R6/R8/R11/R12: ~358 us). 4 waves, i8 MFMA 16x16x64 recurrent matvec, 8-deep
// acc select, fused gate chain with gamma folded into pre. Step ~859 cyc =
// 320 (per-SIMD MFMA pipe) + ~535 (serial recurrence: ds_read + select + gates + write
// + barrier) — additive, confirmed by R10's pairing experiment (640+534=1174). ----------------
__global__ __launch_bounds__(256) void lstm_kernel(
    const float* __restrict__ w_hh_f, const float* __restrict__ w_hh_b,
    const float* __restrict__ pre, float* __restrict__ h_out)
{
    const int bid = blockIdx.x;          // 0..31
    const int b   = bid & 15;
    const int dir = bid >> 4;
    const float* w_hh = dir ? w_hh_b : w_hh_f;
    const int tid = threadIdx.x;
    const int wave = tid >> 6, lane = tid & 63, l15 = lane & 15, quad = lane >> 4;
    const bool own = ((l15 & 1) == 0);               // lane pairs share a cell; even l15 writes
    const int cellj = wave * 32 + ((l15 >> 1) << 2) + quad;
    const int m0 = (l15 >> 1) & 1, m1 = (l15 >> 2) & 1, m2 = (l15 >> 3) & 1;  // select bits

    __shared__ __attribute__((aligned(16))) signed char h8[2][128];   // double-buffered i8 h(t)

    // A-fragments (i8): perm row s = wave*128 + mt*16 + l15; W_hh row = (s&3)*128 + (s>>2)
    // frag element: byte e (=d*4+bi) of kt covers k = kt*64 + quad*16 + e
    i32x4 afrag[8][2];
    #pragma unroll
    for (int mt = 0; mt < 8; ++mt) {
        int s = wave * 128 + mt * 16 + l15;
        const float* wrow = w_hh + (size_t)((s & 3) * 128 + (s >> 2)) * 128;
        #pragma unroll
        for (int kt = 0; kt < 2; ++kt) {
            i32x4 v;
            #pragma unroll
            for (int d = 0; d < 4; ++d) {
                int pk = 0;
                #pragma unroll
                for (int bi = 0; bi < 4; ++bi) {
                    int k = kt * 64 + quad * 16 + d * 4 + bi;
                    int q = (int)rintf(wrow[k] * 254.f);
                    pk |= (q & 255) << (bi * 8);
                }
                v[d] = pk;
            }
            afrag[mt][kt] = v;
        }
    }

    if (tid < 64) reinterpret_cast<int*>(h8)[tid] = 0;   // zero both 128B buffers

    const int t0 = dir ? 1000 : 0;
    const ptrdiff_t pre_sstride  = dir ? -16384 : 16384;   // floats per step
    const ptrdiff_t hout_sstride = dir ? -2048  : 2048;    // floats per step
    const float* pre_base = pre + ((size_t)(t0 * 2 + dir) * 16 + b) * 512 + (size_t)cellj * 4;
    float* hout_base = h_out + (((size_t)dir * 1001 + t0) * 16 + b) * 128 + cellj;

    float cstate = 0.f;
    const float L2E = 1.4426950408889634f;
    const float DF = 1.0f / (254.f * 127.f);
    const float CI = -L2E * DF;          // i, f, o gates
    const float CG = -2.f * L2E * DF;    // g gate

    auto body = [&](int s, f32x4 P) {
        const signed char* hb = h8[s & 1];
        i32x4 b0 = *reinterpret_cast<const i32x4*>(&hb[quad * 16]);
        i32x4 b1 = *reinterpret_cast<const i32x4*>(&hb[64 + quad * 16]);

        i32x4 acc[8] = {};
        #pragma unroll
        for (int mt = 0; mt < 8; ++mt)
            acc[mt] = __builtin_amdgcn_mfma_i32_16x16x64_i8(afrag[mt][0], b0, acc[mt], 0, 0, 0);
        #pragma unroll
        for (int mt = 0; mt < 8; ++mt)
            acc[mt] = __builtin_amdgcn_mfma_i32_16x16x64_i8(afrag[mt][1], b1, acc[mt], 0, 0, 0);

        // z4 = acc[l15>>1] (3-level select; valid for this lane's cell)
        i32x4 ta = m0 ? acc[1] : acc[0];
        i32x4 tb = m0 ? acc[3] : acc[2];
        i32x4 tc = m0 ? acc[5] : acc[4];
        i32x4 td = m0 ? acc[7] : acc[6];
        i32x4 ua = m1 ? tb : ta;
        i32x4 ub = m1 ? td : tc;
        i32x4 z4 = m2 ? ub : ua;

        // gates: pre already carries gamma_g*(z_in+bias); one cvt+fma per gate
        float ai = fmaf((float)z4[0], CI, P[0]);
        float af_ = fmaf((float)z4[1], CI, P[1]);
        float ag = fmaf((float)z4[2], CG, P[2]);
        float ao = fmaf((float)z4[3], CI, P[3]);
        float A = __builtin_amdgcn_exp2f(ai);
        float B = __builtin_amdgcn_exp2f(af_);
        float C = __builtin_amdgcn_exp2f(ag);
        float D = __builtin_amdgcn_exp2f(ao);
        float Pp = (1.f + A) * (1.f + C);
        float Q = 1.f + B;
        float cn = (cstate * Pp + (1.f - C) * Q) * __builtin_amdgcn_rcpf(Pp * Q);
        cstate = cn;
        float E = __builtin_amdgcn_exp2f(-2.f * L2E * cn);
        float h = (1.f - E) * __builtin_amdgcn_rcpf((1.f + D) * (1.f + E));

        if (own) {
            h8[(s + 1) & 1][cellj] = (signed char)(int)rintf(h * 127.f);
            hout_base[(ptrdiff_t)s * hout_sstride] = h;   // fire-and-forget
        }
    };

    auto load_pre = [&](int sidx) -> f32x4 {
        return *reinterpret_cast<const f32x4*>(pre_base + (ptrdiff_t)sidx * pre_sstride);
    };

    f32x4 P0 = load_pre(0), P1 = load_pre(1), P2 = load_pre(2), P3 = load_pre(3);
    __syncthreads();   // h8 init visible

    for (int s = 0; s < 1000; s += 4) {   // pre padded +-4 steps: no bounds checks
        body(s, P0);     P0 = load_pre(s + 4); sync_lds();
        body(s + 1, P1); P1 = load_pre(s + 5); sync_lds();
        body(s + 2, P2); P2 = load_pre(s + 6); sync_lds();
        body(s + 3, P3); P3 = load_pre(s + 7); sync_lds();
    }
    body(1000, P0);
}

// ---------------- LayerNorm + out projection via MFMA: 1001 blocks x 16 rows. ----------------
__global__ __launch_bounds__(256) void out_kernel(
    const float* __restrict__ h_out, const float* __restrict__ ln_g, const float* __restrict__ ln_b,
    const float* __restrict__ out_w, const float* __restrict__ out_b, float* __restrict__ out)
{
    __shared__ __bf16 hn_lds[16 * 264];   // stride 264 -> 2-way on b128 = free
    const int tid = threadIdx.x;
    const int wave = tid >> 6, lane = tid & 63, l15 = lane & 15, quad = lane >> 4;

    float lg0 = ln_g[lane],        lb0 = ln_b[lane];
    float lg1 = ln_g[64 + lane],   lb1 = ln_b[64 + lane];
    float lg2 = ln_g[128 + lane],  lb2 = ln_b[128 + lane];
    float lg3 = ln_g[192 + lane],  lb3 = ln_b[192 + lane];

    #pragma unroll
    for (int rr = 0; rr < 4; ++rr) {
        int wrow = wave * 4 + rr;
        int r = blockIdx.x * 16 + wrow;            // 1001*16 = 16016 exactly: no guard
        int b = r / 1001, t = r - b * 1001;
        size_t basef = ((size_t)t * 16 + b) * 128;            // dir 0
        size_t baseb = ((size_t)(1001 + t) * 16 + b) * 128;   // dir 1
        float h0 = h_out[basef + lane];
        float h1 = h_out[basef + 64 + lane];
        float h2 = h_out[baseb + lane];
        float h3 = h_out[baseb + 64 + lane];
        float s1 = h0 + h1 + h2 + h3;
        float s2 = h0 * h0 + h1 * h1 + h2 * h2 + h3 * h3;
        #pragma unroll
        for (int m = 32; m >= 1; m >>= 1) {
            s1 += __shfl_xor(s1, m, 64);
            s2 += __shfl_xor(s2, m, 64);
        }
        float mu = s1 * (1.f / 256.f);
        float var = s2 * (1.f / 256.f) - mu * mu;   // biased var, matches jnp var
        float rstd = rsqrtf(var + 1e-5f);
        hn_lds[wrow * 264 + lane]       = (__bf16)((h0 - mu) * rstd * lg0 + lb0);
        hn_lds[wrow * 264 + 64 + lane]  = (__bf16)((h1 - mu) * rstd * lg1 + lb1);
        hn_lds[wrow * 264 + 128 + lane] = (__bf16)((h2 - mu) * rstd * lg2 + lb2);
        hn_lds[wrow * 264 + 192 + lane] = (__bf16)((h3 - mu) * rstd * lg3 + lb3);
    }
    __syncthreads();

    // GEMM: out[16 rows][64 cols] = hn(16x256) . out_w(64x256)^T; wave covers 16 cols
    const int o = wave * 16 + l15;
    f32x4 accA = {}, accB = {};
    #pragma unroll
    for (int kt = 0; kt < 8; ++kt) {
        bf16x8 a = *reinterpret_cast<const bf16x8*>(&hn_lds[l15 * 264 + kt * 32 + quad * 8]);
        const float* wp = out_w + (size_t)o * 256 + kt * 32 + quad * 8;
        bf16x8 bv;
        #pragma unroll
        for (int e = 0; e < 8; ++e) bv[e] = (__bf16)wp[e];
        if (kt & 1) accB = __builtin_amdgcn_mfma_f32_16x16x32_bf16(a, bv, accB, 0, 0, 0);
        else        accA = __builtin_amdgcn_mfma_f32_16x16x32_bf16(a, bv, accA, 0, 0, 0);
    }
    f32x4 acc = accA + accB;
    float ob = out_b[o];
    #pragma unroll
    for (int rc = 0; rc < 4; ++rc) {
        int r = blockIdx.x * 16 + quad * 4 + rc;
        out[(size_t)r * 64 + o] = acc[rc] + ob;
    }
}

extern "C" void kernel_launch(void* const* d_in, const int* in_sizes, int n_in,
                              void* d_out, int out_size, void* d_ws, size_t ws_size,
                              hipStream_t stream) {
    const float* x      = (const float*)d_in[0];
    const float* f0     = (const float*)d_in[1];
    const float* w_ih_f = (const float*)d_in[2];
    const float* w_hh_f = (const float*)d_in[3];
    const float* b_f    = (const float*)d_in[4];
    const float* w_ih_b = (const float*)d_in[5];
    const float* w_hh_b = (const float*)d_in[6];
    const float* b_b    = (const float*)d_in[7];
    const float* ln_g   = (const float*)d_in[8];
    const float* ln_b   = (const float*)d_in[9];
    const float* out_w  = (const float*)d_in[10];
    const float* out_b  = (const float*)d_in[11];
    float* out = (float*)d_out;

    char* ws = (char*)d_ws;
    size_t off = 0;
    auto alloc = [&](size_t bytes) { size_t o = off; off = (off + bytes + 255) & ~(size_t)255; return o; };
    __bf16* A     = (__bf16*)(ws + alloc((size_t)16128 * 960 * 2));
    __bf16* BT    = (__bf16*)(ws + alloc((size_t)2048 * 960 * 2));
    __bf16* Espec = (__bf16*)(ws + alloc((size_t)16128 * 1024 * 2));
    __bf16* feat  = (__bf16*)(ws + alloc((size_t)16128 * 320 * 2));
    __bf16* WT    = (__bf16*)(ws + alloc((size_t)1024 * 320 * 2));
    // pre padded +-4 timesteps (8 dir-slots each side) so the depth-4 prefetch stays in-buffer
    float*  preA  = (float*)(ws + alloc((size_t)(1001 * 2 + 16) * 16 * 512 * 4));
    float*  pre   = preA + (size_t)8 * 16 * 512;
    float*  h_out = (float*)(ws + alloc((size_t)2 * 1001 * 16 * 128 * 4));
    (void)ws_size; (void)in_sizes; (void)n_in; (void)out_size;

    prep_kernel <<<39200, 256, 0, stream>>>(x, w_ih_f, w_ih_b, BT, A, WT);
    gemm_kernel <<<2048, 256, 0, stream>>>(A, BT, 960, 15, 0, Espec, nullptr, nullptr, nullptr);
    build_feat  <<<16016, 256, 0, stream>>>(f0, Espec, feat);
    gemm_kernel <<<dim3(8, 126), 256, 0, stream>>>(feat, WT, 320, 5, 1, nullptr, pre, b_f, b_b);
    lstm_kernel <<<32, 256, 0, stream>>>(w_hh_f, w_hh_b, pre, h_out);
    out_kernel  <<<1001, 256, 0, stream>>>(h_out, ln_g, ln_b, out_w, out_b, out);
}